// Round 1
// baseline (365.379 us; speedup 1.0000x reference)
//
#include <hip/hip_runtime.h>
#include <stdint.h>

#define EPSN 1e-12f

// ---- bf16 helpers (round-to-nearest-even) ----
__device__ __forceinline__ unsigned short f2bf(float f) {
  union { float f; unsigned int u; } v; v.f = f;
  unsigned int u = v.u + 0x7FFFu + ((v.u >> 16) & 1u);
  return (unsigned short)(u >> 16);
}
__device__ __forceinline__ float bf2f(unsigned short h) {
  union { unsigned int u; float f; } v; v.u = ((unsigned int)h) << 16;
  return v.f;
}

// ---- workspace layout (float offsets) ----
#define WQT_OFF 0                       // wqT[c][o]  258*1024
#define WKT_OFF (258 * 1024)            // wkT[c][o]  258*1024
#define WVT_OFF (2 * 258 * 1024)        // WVt[o][m]  256*64
#define QBAR_OFF (2 * 258 * 1024 + 256 * 64)  // qbar[pixel][16]  16384*16

// =====================================================================
// prep: transpose weights + fuse v@wout^T
// =====================================================================
__global__ __launch_bounds__(256) void prep_kernel(
    const float* __restrict__ wq, const float* __restrict__ wk,
    const float* __restrict__ v, const float* __restrict__ wout,
    float* __restrict__ ws) {
  int idx = blockIdx.x * 256 + threadIdx.x;
  float* wqT = ws + WQT_OFF;
  float* wkT = ws + WKT_OFF;
  float* wvT = ws + WVT_OFF;
  if (idx < 258 * 1024) {
    int c = idx >> 10, o = idx & 1023;
    wqT[idx] = wq[o * 258 + c];
    wkT[idx] = wk[o * 258 + c];
  }
  if (idx < 256 * 64) {
    int o = idx >> 6, m = idx & 63;
    const float* wo = wout + o * 256;
    const float* vm = v + m * 256;
    float s = 0.f;
    for (int f = 0; f < 256; ++f) s = fmaf(wo[f], vm[f], s);
    wvT[idx] = s;  // WVt[o][m]
  }
}

// =====================================================================
// qproj: per-pixel q projection + normalize + mean over m -> qbar
// block = 1024 threads (16 waves), 64 pixels/block, lane = pixel,
// wave w handles m-groups {w, w+16, w+32, w+48}
// =====================================================================
__global__ __launch_bounds__(1024) void qproj_kernel(
    const float* __restrict__ x, const float* __restrict__ pos,
    const float* __restrict__ bq, float* __restrict__ ws) {
  __shared__ unsigned short xp[258 * 64];  // bf16 staged input, 33 KB
  __shared__ float qbar[64 * 16];          // 4 KB
  const float* wqT = ws + WQT_OFF;
  float* qbar_g = ws + QBAR_OFF;
  const int tid = threadIdx.x;
  const int P0 = blockIdx.x * 64;          // global pixel base
  const int b = P0 >> 12, s0 = P0 & 4095;

  for (int i = tid; i < 258 * 64; i += 1024) {
    int c = i >> 6, p = i & 63;
    float vv = (c < 256) ? x[(((b << 8) + c) << 12) + s0 + p]
                         : pos[((c - 256) << 12) + s0 + p];
    xp[i] = f2bf(vv);
  }
  qbar[tid] = 0.f;  // blockDim==1024 covers all 1024 entries
  __syncthreads();

  const int lane = tid & 63;
  const int wid = __builtin_amdgcn_readfirstlane(tid >> 6);  // force SGPR

  float qsum[16];
#pragma unroll
  for (int j = 0; j < 16; ++j) qsum[j] = 0.f;

  for (int g = 0; g < 4; ++g) {
    const int m = (g << 4) + wid;            // m-group, wave-uniform
    const float* wb = wqT + (m << 4);        // wqT[c*1024 + m*16 + j]
    const float* bb = bq + (m << 4);
    float acc[16];
#pragma unroll
    for (int j = 0; j < 16; ++j) acc[j] = bb[j];
    for (int c = 0; c < 258; ++c) {
      float xv = bf2f(xp[(c << 6) + lane]);
      const float* wc = wb + (c << 10);      // uniform -> scalar loads
#pragma unroll
      for (int j = 0; j < 16; ++j) acc[j] = fmaf(wc[j], xv, acc[j]);
    }
    float n2 = 0.f;
#pragma unroll
    for (int j = 0; j < 16; ++j) n2 = fmaf(acc[j], acc[j], n2);
    float inv = 1.0f / fmaxf(sqrtf(n2), EPSN);
#pragma unroll
    for (int j = 0; j < 16; ++j) qsum[j] = fmaf(acc[j], inv, qsum[j]);
  }
#pragma unroll
  for (int j = 0; j < 16; ++j)
    atomicAdd(&qbar[(lane << 4) + j], qsum[j] * (1.0f / 64.0f));
  __syncthreads();
  // qbar_g[(P0+p)*16 + j] ; LDS layout [p][j] makes this a flat copy
  qbar_g[(P0 << 4) + tid] = qbar[tid];
}

// =====================================================================
// kattn: k projection + normalize + attn + fused (WV^T @ attn) epilogue
// =====================================================================
__global__ __launch_bounds__(1024) void kattn_kernel(
    const float* __restrict__ x, const float* __restrict__ pos,
    const float* __restrict__ bk, const float* __restrict__ bout,
    const float* __restrict__ ws_c, float* __restrict__ out) {
  __shared__ unsigned short xp[258 * 64];  // 33 KB
  __shared__ float qbar[64 * 16];          // 4 KB
  __shared__ float attn[64 * 64];          // [m][p] 16 KB
  const float* wkT = ws_c + WKT_OFF;
  const float* wvT = ws_c + WVT_OFF;
  const float* qbar_g = ws_c + QBAR_OFF;
  const int tid = threadIdx.x;
  const int P0 = blockIdx.x * 64;
  const int b = P0 >> 12, s0 = P0 & 4095;

  for (int i = tid; i < 258 * 64; i += 1024) {
    int c = i >> 6, p = i & 63;
    float vv = (c < 256) ? x[(((b << 8) + c) << 12) + s0 + p]
                         : pos[((c - 256) << 12) + s0 + p];
    xp[i] = f2bf(vv);
  }
  qbar[tid] = qbar_g[(P0 << 4) + tid];
  __syncthreads();

  const int lane = tid & 63;
  const int wid = __builtin_amdgcn_readfirstlane(tid >> 6);

  // preload this pixel's qbar into registers (avoids 32-way LDS conflicts
  // in the hot loop; one-time conflicted read is negligible)
  float qb[16];
#pragma unroll
  for (int j = 0; j < 16; ++j) qb[j] = qbar[(lane << 4) + j];

  for (int g = 0; g < 4; ++g) {
    const int m = (g << 4) + wid;
    const float* wb = wkT + (m << 4);
    const float* bb = bk + (m << 4);
    float acc[16];
#pragma unroll
    for (int j = 0; j < 16; ++j) acc[j] = bb[j];
    for (int c = 0; c < 258; ++c) {
      float xv = bf2f(xp[(c << 6) + lane]);
      const float* wc = wb + (c << 10);
#pragma unroll
      for (int j = 0; j < 16; ++j) acc[j] = fmaf(wc[j], xv, acc[j]);
    }
    float n2 = 0.f;
#pragma unroll
    for (int j = 0; j < 16; ++j) n2 = fmaf(acc[j], acc[j], n2);
    float inv = 1.0f / fmaxf(sqrtf(n2), EPSN);
    float a = 0.f;
#pragma unroll
    for (int j = 0; j < 16; ++j) a = fmaf(qb[j], acc[j], a);
    attn[(m << 6) + lane] = a * inv;
  }
  __syncthreads();

  // epilogue: out[b,o,s0+lane] = x + bout[o] + sum_m WVt[o][m]*attn[m][p]
#pragma unroll 1
  for (int i = 0; i < 16; ++i) {
    const int o = (i << 4) + wid;            // wave-uniform
    const float* wv = wvT + (o << 6);        // uniform -> scalar loads
    float accv = bout[o];
#pragma unroll
    for (int mm = 0; mm < 64; ++mm)
      accv = fmaf(wv[mm], attn[(mm << 6) + lane], accv);
    const int gi = (((b << 8) + o) << 12) + s0 + lane;
    out[gi] = x[gi] + accv;
  }
}

// =====================================================================
extern "C" void kernel_launch(void* const* d_in, const int* in_sizes, int n_in,
                              void* d_out, int out_size, void* d_ws, size_t ws_size,
                              hipStream_t stream) {
  const float* x    = (const float*)d_in[0];
  const float* pos  = (const float*)d_in[1];
  const float* wq   = (const float*)d_in[2];
  const float* bq   = (const float*)d_in[3];
  const float* wk   = (const float*)d_in[4];
  const float* bk   = (const float*)d_in[5];
  const float* v    = (const float*)d_in[6];
  const float* wout = (const float*)d_in[7];
  const float* bout = (const float*)d_in[8];
  float* out = (float*)d_out;
  float* ws  = (float*)d_ws;

  hipLaunchKernelGGL(prep_kernel, dim3(1032), dim3(256), 0, stream,
                     wq, wk, v, wout, ws);
  hipLaunchKernelGGL(qproj_kernel, dim3(256), dim3(1024), 0, stream,
                     x, pos, bq, ws);
  hipLaunchKernelGGL(kattn_kernel, dim3(256), dim3(1024), 0, stream,
                     x, pos, bk, bout, ws, out);
}

// Round 3
// 150.529 us; speedup vs baseline: 2.4273x; 2.4273x over previous
//
#include <hip/hip_runtime.h>
#include <stdint.h>

#define EPSN 1e-12f

typedef float f32x4 __attribute__((ext_vector_type(4)));
typedef __bf16 bf16x8 __attribute__((ext_vector_type(8)));

// ---- bf16 helpers (round-to-nearest-even) ----
__device__ __forceinline__ unsigned short f2bf(float f) {
  union { float f; unsigned int u; } v; v.f = f;
  unsigned int u = v.u + 0x7FFFu + ((v.u >> 16) & 1u);
  return (unsigned short)(u >> 16);
}

// ---- workspace layout (ushort offsets) ----
// wqP: bf16 [1024][288]  (k 0..257 = weights, 258 = bias, 259.. = 0)
// wkP: bf16 [1024][288]
// wvP: bf16 [256][64]    WVt[o][m] = sum_f wout[o][f] * v[m][f]
#define WQP_OFF 0
#define WKP_OFF (1024 * 288)
#define WVP_OFF (2 * 1024 * 288)

// =====================================================================
// prep: pack weights to bf16 (padded, bias-folded) + fuse v@wout^T
// =====================================================================
__global__ __launch_bounds__(256) void prep_kernel(
    const float* __restrict__ wq, const float* __restrict__ bq,
    const float* __restrict__ wk, const float* __restrict__ bk,
    const float* __restrict__ v, const float* __restrict__ wout,
    unsigned short* __restrict__ wsp) {
  int idx = blockIdx.x * 256 + threadIdx.x;
  if (idx < 1024 * 288) {
    int o = idx / 288, k = idx - o * 288;
    float vq, vk;
    if (k < 258)      { vq = wq[o * 258 + k]; vk = wk[o * 258 + k]; }
    else if (k == 258){ vq = bq[o];           vk = bk[o]; }
    else              { vq = 0.f;             vk = 0.f; }
    wsp[WQP_OFF + idx] = f2bf(vq);
    wsp[WKP_OFF + idx] = f2bf(vk);
  }
  if (idx < 256 * 64) {
    int o = idx >> 6, m = idx & 63;
    const float* wo = wout + o * 256;
    const float* vm = v + m * 256;
    float s = 0.f;
    for (int f = 0; f < 256; ++f) s = fmaf(wo[f], vm[f], s);
    wsp[WVP_OFF + idx] = f2bf(s);  // [o][m]
  }
}

// =====================================================================
// fused: stage xp -> q MFMA -> norm/qbar -> k MFMA -> attn -> epilogue MFMA
// block = 1024 threads (16 waves), 64 pixels/block
// wave w: projection o-range [w*64, w*64+64) = m-groups [w*4, w*4+4)
// =====================================================================
#define KP 296  // xp row stride in bf16 elems (16B-aligned rows for ds_read_b128)

__global__ __launch_bounds__(1024) void fused_kernel(
    const float* __restrict__ x, const float* __restrict__ pos,
    const unsigned short* __restrict__ wsp, const float* __restrict__ bout,
    float* __restrict__ out) {
  __shared__ __align__(16) unsigned short xp[64 * KP];     // 37888 B
  __shared__ __align__(16) float qbarL[16 * 66];           // 4224 B
  __shared__ __align__(16) unsigned short attnT[64 * 72];  // 9216 B [p][m]
  __shared__ float boutL[256];

  const int tid = threadIdx.x;
  const int lane = tid & 63;
  const int wid = __builtin_amdgcn_readfirstlane(tid >> 6);
  const int col = lane & 15, quad = lane >> 4;
  const int P0 = blockIdx.x * 64;
  const int b = P0 >> 12, s0 = P0 & 4095;

  // ---- stage xp[p][c] (bf16) ----
  for (int i = tid; i < 64 * KP; i += 1024) {
    int c = i >> 6, p = i & 63;
    float vv;
    if (c < 256)        vv = x[(b * 256 + c) * 4096 + s0 + p];
    else if (c < 258)   vv = pos[(c - 256) * 4096 + s0 + p];
    else if (c == 258)  vv = 1.0f;   // bias channel
    else                vv = 0.0f;
    xp[p * KP + c] = f2bf(vv);
  }
  if (tid < 256) boutL[tid] = bout[tid];
  // BUGFIX R2: 16*66 = 1056 > blockDim (1024) — must stride the init loop,
  // else rows j=15, p>=34 start from garbage and poison qbar via atomicAdd.
  for (int i = tid; i < 16 * 66; i += 1024) qbarL[i] = 0.f;
  __syncthreads();

  // ================= q phase =================
  f32x4 acc[4][4];
#pragma unroll
  for (int ot = 0; ot < 4; ++ot)
#pragma unroll
    for (int nt = 0; nt < 4; ++nt) acc[ot][nt] = (f32x4)0.f;

  {
    const unsigned short* wbase = wsp + WQP_OFF + (wid * 64 + col) * 288 + quad * 8;
#pragma unroll 1
    for (int ks = 0; ks < 9; ++ks) {
      const int kb = ks * 32;
      bf16x8 av[4], bv[4];
#pragma unroll
      for (int ot = 0; ot < 4; ++ot)
        av[ot] = *(const bf16x8*)(wbase + ot * 16 * 288 + kb);
#pragma unroll
      for (int nt = 0; nt < 4; ++nt)
        bv[nt] = *(const bf16x8*)(&xp[(nt * 16 + col) * KP + kb + quad * 8]);
#pragma unroll
      for (int ot = 0; ot < 4; ++ot)
#pragma unroll
        for (int nt = 0; nt < 4; ++nt)
          acc[ot][nt] = __builtin_amdgcn_mfma_f32_16x16x32_bf16(av[ot], bv[nt], acc[ot][nt], 0, 0, 0);
    }
  }

  // normalize each m-group (16 j = tile rows) per pixel; accumulate qbar partials
  {
    float qsum[4][4];  // [nt][r]
#pragma unroll
    for (int nt = 0; nt < 4; ++nt)
#pragma unroll
      for (int r = 0; r < 4; ++r) qsum[nt][r] = 0.f;
#pragma unroll
    for (int ot = 0; ot < 4; ++ot) {
#pragma unroll
      for (int nt = 0; nt < 4; ++nt) {
        f32x4 a = acc[ot][nt];
        float s = a[0]*a[0] + a[1]*a[1] + a[2]*a[2] + a[3]*a[3];
        s += __shfl_xor(s, 16, 64);
        s += __shfl_xor(s, 32, 64);
        float inv = 1.0f / fmaxf(sqrtf(s), EPSN);
#pragma unroll
        for (int r = 0; r < 4; ++r) qsum[nt][r] = fmaf(a[r], inv, qsum[nt][r]);
      }
    }
#pragma unroll
    for (int nt = 0; nt < 4; ++nt)
#pragma unroll
      for (int r = 0; r < 4; ++r)
        atomicAdd(&qbarL[(quad * 4 + r) * 66 + nt * 16 + col], qsum[nt][r] * (1.0f / 64.0f));
  }
  __syncthreads();

  // ================= k phase =================
#pragma unroll
  for (int ot = 0; ot < 4; ++ot)
#pragma unroll
    for (int nt = 0; nt < 4; ++nt) acc[ot][nt] = (f32x4)0.f;

  {
    const unsigned short* wbase = wsp + WKP_OFF + (wid * 64 + col) * 288 + quad * 8;
#pragma unroll 1
    for (int ks = 0; ks < 9; ++ks) {
      const int kb = ks * 32;
      bf16x8 av[4], bv[4];
#pragma unroll
      for (int ot = 0; ot < 4; ++ot)
        av[ot] = *(const bf16x8*)(wbase + ot * 16 * 288 + kb);
#pragma unroll
      for (int nt = 0; nt < 4; ++nt)
        bv[nt] = *(const bf16x8*)(&xp[(nt * 16 + col) * KP + kb + quad * 8]);
#pragma unroll
      for (int ot = 0; ot < 4; ++ot)
#pragma unroll
        for (int nt = 0; nt < 4; ++nt)
          acc[ot][nt] = __builtin_amdgcn_mfma_f32_16x16x32_bf16(av[ot], bv[nt], acc[ot][nt], 0, 0, 0);
    }
  }

  {
    float qb[4][4];  // [nt][r]
#pragma unroll
    for (int nt = 0; nt < 4; ++nt)
#pragma unroll
      for (int r = 0; r < 4; ++r)
        qb[nt][r] = qbarL[(quad * 4 + r) * 66 + nt * 16 + col];

#pragma unroll
    for (int ot = 0; ot < 4; ++ot) {
      const int m = wid * 4 + ot;
#pragma unroll
      for (int nt = 0; nt < 4; ++nt) {
        f32x4 a = acc[ot][nt];
        float s2 = a[0]*a[0] + a[1]*a[1] + a[2]*a[2] + a[3]*a[3];
        float sp = qb[nt][0]*a[0] + qb[nt][1]*a[1] + qb[nt][2]*a[2] + qb[nt][3]*a[3];
        s2 += __shfl_xor(s2, 16, 64);
        s2 += __shfl_xor(s2, 32, 64);
        sp += __shfl_xor(sp, 16, 64);
        sp += __shfl_xor(sp, 32, 64);
        float attn = sp / fmaxf(sqrtf(s2), EPSN);
        if (quad == 0) attnT[(nt * 16 + col) * 72 + m] = f2bf(attn);
      }
    }
  }
  __syncthreads();

  // ================= epilogue: out = x + bout + WVt @ attn =================
  {
    f32x4 e[4];
#pragma unroll
    for (int nt = 0; nt < 4; ++nt) e[nt] = (f32x4)0.f;
    const unsigned short* wvb = wsp + WVP_OFF + (wid * 16 + col) * 64 + quad * 8;
#pragma unroll
    for (int ks = 0; ks < 2; ++ks) {
      bf16x8 av = *(const bf16x8*)(wvb + ks * 32);
#pragma unroll
      for (int nt = 0; nt < 4; ++nt) {
        bf16x8 bv = *(const bf16x8*)(&attnT[(nt * 16 + col) * 72 + ks * 32 + quad * 8]);
        e[nt] = __builtin_amdgcn_mfma_f32_16x16x32_bf16(av, bv, e[nt], 0, 0, 0);
      }
    }
#pragma unroll
    for (int nt = 0; nt < 4; ++nt) {
#pragma unroll
      for (int r = 0; r < 4; ++r) {
        const int o = wid * 16 + quad * 4 + r;
        const int p = nt * 16 + col;
        const int gi = (b * 256 + o) * 4096 + s0 + p;
        out[gi] = x[gi] + boutL[o] + e[nt][r];
      }
    }
  }
}

// =====================================================================
extern "C" void kernel_launch(void* const* d_in, const int* in_sizes, int n_in,
                              void* d_out, int out_size, void* d_ws, size_t ws_size,
                              hipStream_t stream) {
  const float* x    = (const float*)d_in[0];
  const float* pos  = (const float*)d_in[1];
  const float* wq   = (const float*)d_in[2];
  const float* bq   = (const float*)d_in[3];
  const float* wk   = (const float*)d_in[4];
  const float* bk   = (const float*)d_in[5];
  const float* v    = (const float*)d_in[6];
  const float* wout = (const float*)d_in[7];
  const float* bout = (const float*)d_in[8];
  float* out = (float*)d_out;
  unsigned short* wsp = (unsigned short*)d_ws;

  hipLaunchKernelGGL(prep_kernel, dim3(1152), dim3(256), 0, stream,
                     wq, bq, wk, bk, v, wout, wsp);
  hipLaunchKernelGGL(fused_kernel, dim3(256), dim3(1024), 0, stream,
                     x, pos, wsp, bout, out);
}